// Round 11
// baseline (220.917 us; speedup 1.0000x reference)
//
#include <hip/hip_runtime.h>
#include <cstdint>
#include <cstddef>

// ---------------------------------------------------------------------------
// Pre-LN multi-head attention block. B=4, N=2048, D=768, H=12, Dh=64.
// bf16 MFMA 16x16x32; fp32 in/out. XOR-swizzled LDS tiles.
// attn: r9-exact (best measured 78.9us): 3-buffer staging, counted
// vmcnt(4) + raw s_barrier, runtime buffer rotation, P in registers,
// PV via k=16 MFMAs, row-sums via ones-B MFMA, setprio on MFMA clusters.
// gemm_qkv: 768 blocks (8*96 XCD-bijective), QK 128x128 + V 64x128 per
// block (zero tail), with cross-phase prefetch (phase-2 tile 0 staged
// under phase-1's register-only epilogue).
// LN: wave-per-row one-pass. gemm_out: 768 blocks, XCD relabel.
// ---------------------------------------------------------------------------

#define SEQ    2048
#define NBATCH 4
#define DMODEL 768
#define NHEADS 12
#define DHEAD  64
#define MROWS  (NBATCH * SEQ)   // 8192
#define NQKV   (3 * DMODEL)     // 2304
#define KT     64               // attention key-tile
#define NT     (SEQ / KT)       // 32

using f32x4  = __attribute__((ext_vector_type(4))) float;
using u16x8  = __attribute__((ext_vector_type(8))) unsigned short;
using s16x8  = __attribute__((ext_vector_type(8))) short;
using u16x4  = __attribute__((ext_vector_type(4))) unsigned short;
using s16x4  = __attribute__((ext_vector_type(4))) short;

__device__ __forceinline__ unsigned short f2bf(float f) {
  union { float f; unsigned int u; } x; x.f = f;
  unsigned int r = x.u + 0x7fffu + ((x.u >> 16) & 1u);   // RNE
  return (unsigned short)(r >> 16);
}

#if defined(__has_builtin)
#if __has_builtin(__builtin_amdgcn_cvt_pk_bf16_f32)
#define HAVE_PK_BF16 1
#endif
#if __has_builtin(__builtin_amdgcn_exp2f)
#define HAVE_EXP2 1
#endif
#if __has_builtin(__builtin_amdgcn_mfma_f32_16x16x16bf16_1k)
#define HAVE_MFMA_16X16X16_BF16 1
#endif
#endif

__device__ __forceinline__ unsigned int pk_bf16(float a, float b) {
#ifdef HAVE_PK_BF16
  auto v = __builtin_amdgcn_cvt_pk_bf16_f32(a, b);
  union { decltype(v) v2; unsigned int u; } c; c.v2 = v; return c.u;
#else
  return (unsigned int)f2bf(a) | ((unsigned int)f2bf(b) << 16);
#endif
}

// 2^x in one v_exp_f32 (q is pre-scaled by 0.125*log2(e))
__device__ __forceinline__ float fexp2(float x) {
#ifdef HAVE_EXP2
  return __builtin_amdgcn_exp2f(x);
#else
  return exp2f(x);
#endif
}

__device__ __forceinline__ f32x4 mfma16(u16x8 a, u16x8 b, f32x4 c) {
  return __builtin_amdgcn_mfma_f32_16x16x32_bf16((s16x8)a, (s16x8)b, c, 0, 0, 0);
}

// k=16 variant: A/B are 4 bf16 (2 VGPRs); lane l holds row/col l&15,
// k = (l>>4)*4 + j. C/D layout identical to the x32 family.
__device__ __forceinline__ f32x4 mfma16k16(u16x4 a, u16x4 b, f32x4 c) {
#ifdef HAVE_MFMA_16X16X16_BF16
  return __builtin_amdgcn_mfma_f32_16x16x16bf16_1k((s16x4)a, (s16x4)b, c, 0, 0, 0);
#else
  f32x4 d;
  asm("v_mfma_f32_16x16x16_bf16 %0, %1, %2, %3"
      : "=v"(d) : "v"(a), "v"(b), "v"(c));
  return d;
#endif
}

// async global->LDS, 16B/lane; lane i writes LDS base + i*16
__device__ __forceinline__ void gl_lds16(const void* g, void* l) {
  __builtin_amdgcn_global_load_lds(
      (const __attribute__((address_space(1))) void*)g,
      (__attribute__((address_space(3))) void*)l, 16, 0, 0);
}

// ---------------------------------------------------------------------------
// Fused LayerNorm + both weight transposes, one dispatch.
// Blocks [0,2048): LN, 4 rows/block, one row per WAVE (no barriers, no LDS):
//   float4 loads, one-pass mean/var via shfl_xor butterfly, uint2 bf16 stores.
// Blocks [2048,3776): transpose W_qkv (N=2304); [3776,4352): W_out (N=768).
// ---------------------------------------------------------------------------
__global__ __launch_bounds__(256) void lntconv_kernel(
    const float* __restrict__ x, const float* __restrict__ g,
    const float* __restrict__ bb, unsigned short* __restrict__ xn,
    const float* __restrict__ Wq, const float* __restrict__ Wo,
    unsigned short* __restrict__ Wqt, unsigned short* __restrict__ Wot) {
  __shared__ float tile[32][33];               // tconv only
  const int t = threadIdx.x;
  int id = blockIdx.x;
  if (id < 2048) {                             // ---- LN: one row per wave
    const int wid = t >> 6, l = t & 63;
    const int row = id * 4 + wid;
    const float4* xr = (const float4*)(x + (size_t)row * DMODEL);
    float4 xa = xr[l], xb2 = xr[64 + l], xc = xr[128 + l];
    float s = (xa.x + xa.y) + (xa.z + xa.w) + (xb2.x + xb2.y) + (xb2.z + xb2.w)
            + (xc.x + xc.y) + (xc.z + xc.w);
    float q = xa.x * xa.x + xa.y * xa.y + xa.z * xa.z + xa.w * xa.w
            + xb2.x * xb2.x + xb2.y * xb2.y + xb2.z * xb2.z + xb2.w * xb2.w
            + xc.x * xc.x + xc.y * xc.y + xc.z * xc.z + xc.w * xc.w;
#pragma unroll
    for (int o = 32; o; o >>= 1) { s += __shfl_xor(s, o); q += __shfl_xor(q, o); }
    const float mu = s * (1.0f / DMODEL);
    const float var = q * (1.0f / DMODEL) - mu * mu;
    const float rstd = rsqrtf(var + 1e-5f);
    const float4* gp = (const float4*)g;
    const float4* bp = (const float4*)bb;
    uint2* dst = (uint2*)(xn + (size_t)row * DMODEL);
#pragma unroll
    for (int c = 0; c < 3; ++c) {
      float4 xv = (c == 0) ? xa : (c == 1) ? xb2 : xc;
      float4 gv = gp[c * 64 + l], bv = bp[c * 64 + l];
      float y0 = (xv.x - mu) * rstd * gv.x + bv.x;
      float y1 = (xv.y - mu) * rstd * gv.y + bv.y;
      float y2 = (xv.z - mu) * rstd * gv.z + bv.z;
      float y3 = (xv.w - mu) * rstd * gv.w + bv.w;
      uint2 pk; pk.x = pk_bf16(y0, y1); pk.y = pk_bf16(y2, y3);
      dst[c * 64 + l] = pk;
    }
    return;
  }
  // ---- transpose + fp32->bf16: W[K=768][N] -> Wt[N][768]
  id -= 2048;
  const float* W; unsigned short* Wt; int N, n0, k0;
  if (id < 1728) { W = Wq; Wt = Wqt; N = NQKV;   n0 = (id % 72) * 32; k0 = (id / 72) * 32; }
  else { id -= 1728; W = Wo; Wt = Wot; N = DMODEL; n0 = (id % 24) * 32; k0 = (id / 24) * 32; }
  const int tx = t & 31, ty = t >> 5;
#pragma unroll
  for (int r = 0; r < 4; ++r)
    tile[ty + r * 8][tx] = W[(size_t)(k0 + ty + r * 8) * N + n0 + tx];
  __syncthreads();
#pragma unroll
  for (int r = 0; r < 4; ++r)
    Wt[(size_t)(n0 + ty + r * 8) * DMODEL + k0 + tx] = f2bf(tile[tx][ty + r * 8]);
}

// ---------------------------------------------------------------------------
// Fused QKV GEMM, 768 blocks (XCD-bijective, 768 = 8*96) -> zero tail at
// 3 blocks/CU. Each block:
//  phase 1 (QK, swapped): 128x128 tile of C^T[n_qkv][seq] = Wt · xn^T.
//  phase 2 (V, original): 64x128 slab of xn @ W_qkv cols [1536,2304).
// Cross-phase prefetch: phase-2 tile 0 is staged right after phase-1's
// final barrier (epilogue is register-only), hiding the first-tile DMA
// latency under the 32 epilogue stores. Phase-2 loop stages after compute.
// ---------------------------------------------------------------------------
__global__ __launch_bounds__(256, 3) void gemm_qkv_kernel(
    const unsigned short* __restrict__ Wt, const unsigned short* __restrict__ xn,
    const float* __restrict__ bias, unsigned short* __restrict__ qb,
    unsigned short* __restrict__ kb, unsigned short* __restrict__ vt) {
  __shared__ alignas(16) unsigned short As[128 * 64];
  __shared__ alignas(16) unsigned short Bs[128 * 64];
  const int t = threadIdx.x, wid = t >> 6, l = t & 63, quad = l >> 4, ll = l & 15;
  const int bid = blockIdx.x;
  const int w = (bid & 7) * 96 + (bid >> 3);   // XCD-bijective (768 = 8*96)
  const int srow = l >> 3, sblk = (l & 7) ^ srow;

  // phase-2 geometry (needed early for the cross-phase prefetch)
  const int m0 = (w & 127) * 64;               // seq base (128 slabs)
  const int n0 = 2 * DMODEL + (w >> 7) * 128;  // vdim base in [1536,2304)
  const unsigned short* A2 = xn + (size_t)m0 * DMODEL;
  const unsigned short* B2 = Wt + (size_t)n0 * DMODEL;

  auto stage2 = [&](int k0) {                  // stage one phase-2 tile
#pragma unroll
    for (int cc = 0; cc < 2; ++cc) {           // A: 64 rows = 8 calls
      int call = wid * 2 + cc;
      int r = call * 8 + srow;
      gl_lds16(A2 + (size_t)r * DMODEL + k0 + sblk * 8, &As[call * 512]);
    }
#pragma unroll
    for (int cc = 0; cc < 4; ++cc) {           // B: 128 rows = 16 calls
      int call = wid * 4 + cc;
      int r = call * 8 + srow;
      gl_lds16(B2 + (size_t)r * DMODEL + k0 + sblk * 8, &Bs[call * 512]);
    }
  };

  // ================= phase 1: QK tile (swapped orientation) ================
  {
    const int a0 = (w % 12) * 128;             // n_qkv base in [0,1536)
    const int b0 = (w / 12) * 128;             // seq base
    const unsigned short* Ap = Wt + (size_t)a0 * DMODEL;
    const unsigned short* Bp = xn + (size_t)b0 * DMODEL;
    const int wa = (wid >> 1) * 64, wb = (wid & 1) * 64;
    f32x4 acc[4][4] = {};
    for (int k0 = 0; k0 < DMODEL; k0 += 64) {
#pragma unroll
      for (int cc = 0; cc < 4; ++cc) {
        int call = wid * 4 + cc;
        int r = call * 8 + srow;
        gl_lds16(Ap + (size_t)r * DMODEL + k0 + sblk * 8, &As[call * 512]);
        gl_lds16(Bp + (size_t)r * DMODEL + k0 + sblk * 8, &Bs[call * 512]);
      }
      __syncthreads();
#pragma unroll
      for (int ks = 0; ks < 2; ++ks) {
        u16x8 af[4], bf[4];
#pragma unroll
        for (int i = 0; i < 4; ++i) {
          int ra = wa + i * 16 + ll, rb = wb + i * 16 + ll;
          int blk = (ks * 4 + quad) ^ (ll & 7);
          af[i] = *(const u16x8*)&As[ra * 64 + blk * 8];
          bf[i] = *(const u16x8*)&Bs[rb * 64 + blk * 8];
        }
#pragma unroll
        for (int mi = 0; mi < 4; ++mi)
#pragma unroll
          for (int ni = 0; ni < 4; ++ni)
            acc[mi][ni] = mfma16(af[mi], bf[ni], acc[mi][ni]);
      }
      __syncthreads();
    }
    // cross-phase prefetch: As/Bs are dead for phase 1 now; epilogue is
    // register-only, so phase-2 tile 0 DMA flies under the stores.
    stage2(0);
    const bool isq = (a0 < DMODEL);
    unsigned short* dst = isq ? qb : kb;
    const float sc = isq ? 0.18033688f : 1.0f;   // q: 0.125 * log2(e)
#pragma unroll
    for (int mi = 0; mi < 4; ++mi) {
      int row0 = a0 + wa + mi * 16 + quad * 4;   // n_qkv (4 consecutive via r)
      float4 bv = *(const float4*)&bias[row0];
      int rr = isq ? row0 : row0 - DMODEL;
      int h = rr >> 6, d0 = rr & 63;
#pragma unroll
      for (int ni = 0; ni < 4; ++ni) {
        int seq = b0 + wb + ni * 16 + ll;
        int b = seq >> 11, i = seq & 2047;
        uint2 pk;
        pk.x = pk_bf16((acc[mi][ni][0] + bv.x) * sc, (acc[mi][ni][1] + bv.y) * sc);
        pk.y = pk_bf16((acc[mi][ni][2] + bv.z) * sc, (acc[mi][ni][3] + bv.w) * sc);
        *(uint2*)&dst[(size_t)((b * NHEADS + h) * SEQ + i) * DHEAD + d0] = pk;
      }
    }
  }

  // ================= phase 2: V slab (original orientation) ================
  {
    const int wm = (wid >> 1) * 32, wn = (wid & 1) * 64;
    f32x4 acc[2][4] = {};
    for (int k0 = 0; k0 < DMODEL; k0 += 64) {
      __syncthreads();                         // staging for this tile done
#pragma unroll
      for (int ks = 0; ks < 2; ++ks) {
        u16x8 af[2], bf[4];
#pragma unroll
        for (int i = 0; i < 2; ++i) {
          int ra = wm + i * 16 + ll;
          int blk = (ks * 4 + quad) ^ (ll & 7);
          af[i] = *(const u16x8*)&As[ra * 64 + blk * 8];
        }
#pragma unroll
        for (int i = 0; i < 4; ++i) {
          int rb = wn + i * 16 + ll;
          int blk = (ks * 4 + quad) ^ (ll & 7);
          bf[i] = *(const u16x8*)&Bs[rb * 64 + blk * 8];
        }
#pragma unroll
        for (int mi = 0; mi < 2; ++mi)
#pragma unroll
          for (int ni = 0; ni < 4; ++ni)
            acc[mi][ni] = mfma16(af[mi], bf[ni], acc[mi][ni]);
      }
      if (k0 + 64 < DMODEL) {
        __syncthreads();                       // all waves done reading
        stage2(k0 + 64);
      }
    }
#pragma unroll
    for (int mi = 0; mi < 2; ++mi) {
      int gm = m0 + wm + mi * 16 + quad * 4;   // seq, 4 consecutive via r
      int b = gm >> 11, i0 = gm & 2047;
#pragma unroll
      for (int ni = 0; ni < 4; ++ni) {
        int gn = n0 + wn + ni * 16 + ll;
        float bv = bias[gn];
        int rem = gn - 2 * DMODEL;
        int h = rem >> 6, d = rem & 63;
        int bh = b * NHEADS + h;
        uint2 pk;
        pk.x = pk_bf16(acc[mi][ni][0] + bv, acc[mi][ni][1] + bv);
        pk.y = pk_bf16(acc[mi][ni][2] + bv, acc[mi][ni][3] + bv);
        *(uint2*)&vt[((size_t)bh * DHEAD + d) * SEQ + i0] = pk;
      }
    }
  }
}

// ---------------------------------------------------------------------------
// Flash attention (r9-exact), streaming sum-of-exp2 (q pre-scaled).
// grid (16 q-tiles, 48 bh), block 256 (4 waves x 32 q-rows, full 64 keys).
// 3-buffer staging, counted s_waitcnt vmcnt(4) + raw s_barrier: each tile's
// global_load_lds get TWO compute phases to land; never drained to 0
// mid-loop. S^T = K·Q^T C-layout == 16x16x16 A-frag, so PV consumes P from
// registers via k=16 MFMAs; row sums via ones-B MFMA. setprio(1) around
// MFMA clusters. LDS 48 KiB -> 3 blocks/CU.
// XCD relabel: 96 contiguous work-ids per XCD -> 6 bh per 4 MiB L2.
// ---------------------------------------------------------------------------
__global__ __launch_bounds__(256, 3) void attn_kernel(
    const unsigned short* __restrict__ qbuf, const unsigned short* __restrict__ kbuf,
    const unsigned short* __restrict__ vtg, unsigned short* __restrict__ ao) {
  __shared__ alignas(16) unsigned short stage[3][2][KT * DHEAD]; // [buf][K,Vt] 48 KiB
  const int t = threadIdx.x, wid = t >> 6, l = t & 63, quad = l >> 4, ll = l & 15;
  const int Lid = blockIdx.y * 16 + blockIdx.x;
  const int w = (Lid & 7) * 96 + (Lid >> 3);   // bijective XCD relabel (768=8*96)
  const int qt = w & 15, bh = w >> 4;
  const unsigned short* qg  = qbuf + ((size_t)bh * SEQ + qt * 128) * DHEAD;
  const unsigned short* kg0 = kbuf + (size_t)bh * SEQ * DHEAD;
  const unsigned short* vt0 = vtg  + (size_t)bh * DHEAD * SEQ;
  const int srow = l >> 3;                    // 0..7
  const int sblk = (l & 7) ^ srow;            // swizzled source block

  // stage Q (16KB over stage[0], swizzled), hoist fragments, free region
  unsigned short* Qs = &stage[0][0][0];
#pragma unroll
  for (int cc = 0; cc < 4; ++cc) {
    int call = wid * 4 + cc;                  // 16 calls x 8 rows = 128 rows
    gl_lds16(qg + (call * 8 + srow) * 64 + sblk * 8, Qs + call * 512);
  }
  __syncthreads();
  u16x8 qf[2][2];                             // [mi][ks]: this wave's 32 q-rows
#pragma unroll
  for (int mi = 0; mi < 2; ++mi)
#pragma unroll
    for (int ks = 0; ks < 2; ++ks) {
      int r = wid * 32 + mi * 16 + ll;
      int blk = (ks * 4 + quad) ^ (ll & 7);
      qf[mi][ks] = *(const u16x8*)&Qs[r * 64 + blk * 8];
    }
  __syncthreads();                            // all waves done reading Q

  auto stage_tile = [&](int buf, int kt2) {   // 4 gl_lds16 per wave
    const unsigned short* kg = kg0 + (size_t)kt2 * KT * DHEAD;
#pragma unroll
    for (int c = 0; c < 2; ++c) {
      int call = wid * 2 + c;                 // 8 calls x 8 rows = 64 rows
      int r = call * 8 + srow;
      gl_lds16(kg + r * 64 + sblk * 8, &stage[buf][0][call * 512]);
      gl_lds16(vt0 + (size_t)r * SEQ + kt2 * KT + sblk * 8, &stage[buf][1][call * 512]);
    }
  };

  f32x4 oacc[2][4] = {};
  f32x4 osum[2] = {};                         // row-sums via ones-B MFMA
  const u16x4 onesb = {0x3f80u, 0x3f80u, 0x3f80u, 0x3f80u};  // bf16(1.0) x4

  stage_tile(0, 0);                           // 4 loads in flight
  stage_tile(1, 1);                           // 8 in flight
  int bufc = 0, bufs = 2;
  for (int kt2 = 0; kt2 < NT; ++kt2) {
    // own 4 loads for THIS tile retired (in-order); next tile's may remain
    if (kt2 + 1 < NT) asm volatile("s_waitcnt vmcnt(4)" ::: "memory");
    else              asm volatile("s_waitcnt vmcnt(0)" ::: "memory");
    __builtin_amdgcn_s_barrier();             // all waves' tile-kt2 staging done
    if (kt2 + 2 < NT) stage_tile(bufs, kt2 + 2);  // 2-ahead prefetch
    const unsigned short* Ks = &stage[bufc][0][0];
    const unsigned short* Vs = &stage[bufc][1][0];

    // S^T = K Q^T  (lane: qrow = mi*16+ll, keys = ni*16 + quad*4 + r)
    f32x4 st[2][4] = {};
    __builtin_amdgcn_s_setprio(1);
#pragma unroll
    for (int ks = 0; ks < 2; ++ks)
#pragma unroll
      for (int ni = 0; ni < 4; ++ni) {
        int r = ni * 16 + ll;
        int blk = (ks * 4 + quad) ^ (ll & 7);
        u16x8 kf = *(const u16x8*)&Ks[r * 64 + blk * 8];
        st[0][ni] = mfma16(kf, qf[0][ks], st[0][ni]);
        st[1][ni] = mfma16(kf, qf[1][ks], st[1][ni]);
      }
    __builtin_amdgcn_s_setprio(0);

    // p = 2^s packed to bf16 in-register == 16x16x16 A-frag for this ni.
    // O += P·V via k=16 MFMAs; Σp via ones-B MFMA (rides the matrix pipe).
#pragma unroll
    for (int ni = 0; ni < 4; ++ni) {
      u16x4 pf[2];
#pragma unroll
      for (int mi = 0; mi < 2; ++mi) {
        float p0 = fexp2(st[mi][ni][0]);
        float p1 = fexp2(st[mi][ni][1]);
        float p2 = fexp2(st[mi][ni][2]);
        float p3 = fexp2(st[mi][ni][3]);
        union { uint2 u; u16x4 v; } cv;
        cv.u.x = pk_bf16(p0, p1);
        cv.u.y = pk_bf16(p2, p3);
        pf[mi] = cv.v;
      }
      // B-frag: V[key = ni*16+quad*4+j][d = di*16+ll]; 8B reads off the
      // staged layout (phys 16B-unit = logical ^ (d&7)); shared across mi.
      const int voff = (((ni * 2 + (quad >> 1)) ^ (ll & 7)) << 3) + (quad & 1) * 4;
      __builtin_amdgcn_s_setprio(1);
      osum[0] = mfma16k16(pf[0], onesb, osum[0]);
      osum[1] = mfma16k16(pf[1], onesb, osum[1]);
#pragma unroll
      for (int di = 0; di < 4; ++di) {
        u16x4 vf = *(const u16x4*)&Vs[(di * 16 + ll) * 64 + voff];
        oacc[0][di] = mfma16k16(pf[0], vf, oacc[0][di]);
        oacc[1][di] = mfma16k16(pf[1], vf, oacc[1][di]);
      }
      __builtin_amdgcn_s_setprio(0);
    }
    bufc = (bufc == 2) ? 0 : bufc + 1;
    bufs = (bufs == 2) ? 0 : bufs + 1;
  }

  // epilogue: O C-layout row = quad*4+r, col d = di*16+ll; osum rows match,
  // so the per-row denominator is already in the right lane — no shuffles.
  const int b = bh / NHEADS, h = bh - b * NHEADS;
#pragma unroll
  for (int mi = 0; mi < 2; ++mi) {
#pragma unroll
    for (int r = 0; r < 4; ++r) {
      float inv = 1.0f / osum[mi][r];
      int row = qt * 128 + wid * 32 + mi * 16 + quad * 4 + r;
      size_t base = ((size_t)(b * SEQ + row)) * DMODEL + h * DHEAD;
#pragma unroll
      for (int di = 0; di < 4; ++di)
        ao[base + di * 16 + ll] = f2bf(oacc[mi][di][r] * inv);
    }
  }
}

// ---------------------------------------------------------------------------
// GEMM-OUT (swapped orientation, 64x128 tile): C^T[n_out][seq] = Woutt·ao^T.
// 768 blocks, XCD-bijective relabel (768 = 8*96): each XCD keeps 8 seq-
// panels of ao (1.5 MiB) + full Woutt (1.2 MiB) L2-resident.
// Lane holds 4 consecutive n_out for one seq -> packed float4 stores.
// ---------------------------------------------------------------------------
__global__ __launch_bounds__(256, 3) void gemm_out_kernel(
    const unsigned short* __restrict__ Wt, const unsigned short* __restrict__ ao,
    const float* __restrict__ bias, float* __restrict__ out) {
  __shared__ alignas(16) unsigned short As[64 * 64];
  __shared__ alignas(16) unsigned short Bs[128 * 64];
  const int t = threadIdx.x, wid = t >> 6, l = t & 63, quad = l >> 4, ll = l & 15;
  const int bid = blockIdx.x;
  const int w = (bid & 7) * 96 + (bid >> 3);   // XCD-bijective relabel (768=8*96)
  const int a0 = (w % 12) * 64;    // n_out base (12 tiles)
  const int b0 = (w / 12) * 128;   // seq base (64 tiles)
  const int wa = (wid >> 1) * 32, wb = (wid & 1) * 64;
  const int srow = l >> 3, sblk = (l & 7) ^ srow;
  f32x4 acc[2][4] = {};
  for (int k0 = 0; k0 < DMODEL; k0 += 64) {
#pragma unroll
    for (int cc = 0; cc < 6; ++cc) {           // 24 calls: 8 A + 16 B
      int call = wid * 6 + cc;
      if (call < 8) {
        int r = call * 8 + srow;
        gl_lds16(Wt + (size_t)(a0 + r) * DMODEL + k0 + sblk * 8, &As[call * 512]);
      } else {
        int c2 = call - 8;
        int r = c2 * 8 + srow;
        gl_lds16(ao + (size_t)(b0 + r) * DMODEL + k0 + sblk * 8, &Bs[c2 * 512]);
      }
    }
    __syncthreads();
#pragma unroll
    for (int ks = 0; ks < 2; ++ks) {
      u16x8 af[2], bf[4];
#pragma unroll
      for (int i = 0; i < 2; ++i) {
        int ra = wa + i * 16 + ll;
        int blk = (ks * 4 + quad) ^ (ll & 7);
        af[i] = *(const u16x8*)&As[ra * 64 + blk * 8];
      }
#pragma unroll
      for (int i = 0; i < 4; ++i) {
        int rb = wb + i * 16 + ll;
        int blk = (ks * 4 + quad) ^ (ll & 7);
        bf[i] = *(const u16x8*)&Bs[rb * 64 + blk * 8];
      }
#pragma unroll
      for (int mi = 0; mi < 2; ++mi)
#pragma unroll
        for (int ni = 0; ni < 4; ++ni)
          acc[mi][ni] = mfma16(af[mi], bf[ni], acc[mi][ni]);
    }
    __syncthreads();
  }
#pragma unroll
  for (int mi = 0; mi < 2; ++mi) {
    int row0 = a0 + wa + mi * 16 + quad * 4;   // n_out, 4 consecutive via r
    float4 bv = *(const float4*)&bias[row0];
#pragma unroll
    for (int ni = 0; ni < 4; ++ni) {
      int seq = b0 + wb + ni * 16 + ll;
      float4 o;
      o.x = acc[mi][ni][0] + bv.x;
      o.y = acc[mi][ni][1] + bv.y;
      o.z = acc[mi][ni][2] + bv.z;
      o.w = acc[mi][ni][3] + bv.w;
      *(float4*)&out[(size_t)seq * DMODEL + row0] = o;
    }
  }
}

// ---------------------------------------------------------------------------
// launch
// ---------------------------------------------------------------------------
extern "C" void kernel_launch(void* const* d_in, const int* in_sizes, int n_in,
                              void* d_out, int out_size, void* d_ws, size_t ws_size,
                              hipStream_t stream) {
  const float* x     = (const float*)d_in[0];
  const float* ln_g  = (const float*)d_in[1];
  const float* ln_b  = (const float*)d_in[2];
  const float* W_qkv = (const float*)d_in[3];
  const float* b_qkv = (const float*)d_in[4];
  const float* W_out = (const float*)d_in[5];
  const float* b_out = (const float*)d_in[6];
  float* out = (float*)d_out;

  char* ws = (char*)d_ws;
  unsigned short* xn    = (unsigned short*)(ws);               // 12,582,912 B
  unsigned short* wqkvt = (unsigned short*)(ws + 12582912);    //  3,538,944 B
  unsigned short* woutt = (unsigned short*)(ws + 16121856);    //  1,179,648 B
  unsigned short* qb    = (unsigned short*)(ws + 17301504);    // 12,582,912 B
  unsigned short* kb    = (unsigned short*)(ws + 29884416);    // 12,582,912 B
  unsigned short* vt    = (unsigned short*)(ws + 42467328);    // 12,582,912 B
  unsigned short* ao    = xn;  // xn dead after the QKV GEMMs

  lntconv_kernel<<<2048 + 2304, 256, 0, stream>>>(x, ln_g, ln_b, xn,
                                                  W_qkv, W_out, wqkvt, woutt);
  gemm_qkv_kernel<<<768, 256, 0, stream>>>(wqkvt, xn, b_qkv, qb, kb, vt);
  attn_kernel<<<dim3(SEQ / 128, NBATCH * NHEADS), 256, 0, stream>>>(qb, kb, vt, ao);
  gemm_out_kernel<<<768, 256, 0, stream>>>(woutt, ao, b_out, out);
}

// Round 12
// 208.375 us; speedup vs baseline: 1.0602x; 1.0602x over previous
//
#include <hip/hip_runtime.h>
#include <cstdint>
#include <cstddef>

// ---------------------------------------------------------------------------
// Pre-LN multi-head attention block. B=4, N=2048, D=768, H=12, Dh=64.
// bf16 MFMA 16x16x32; fp32 in/out. XOR-swizzled LDS tiles.
// attn: r9-exact (best measured 76.5us): 3-buffer staging, counted
// vmcnt(4) + raw s_barrier, runtime buffer rotation, P in registers,
// PV via k=16 MFMAs, row-sums via ones-B MFMA, setprio on MFMA clusters.
// gemm_qkv: 768 blocks (8*96 XCD-bijective), QK 128x128 + V 64x128 per
// block; phase-2 seq-slab is a SUBSET of the same block's phase-1 b0-panel
// (m0 = b0 + half*64), so V-phase xn reads are L2-hot — no cross-XCD
// refetch (was ~6x re-fetch of xn from L3/HBM with the old w&127 map).
// LN: wave-per-row one-pass. gemm_out: 768 blocks, XCD relabel.
// ---------------------------------------------------------------------------

#define SEQ    2048
#define NBATCH 4
#define DMODEL 768
#define NHEADS 12
#define DHEAD  64
#define MROWS  (NBATCH * SEQ)   // 8192
#define NQKV   (3 * DMODEL)     // 2304
#define KT     64               // attention key-tile
#define NT     (SEQ / KT)       // 32

using f32x4  = __attribute__((ext_vector_type(4))) float;
using u16x8  = __attribute__((ext_vector_type(8))) unsigned short;
using s16x8  = __attribute__((ext_vector_type(8))) short;
using u16x4  = __attribute__((ext_vector_type(4))) unsigned short;
using s16x4  = __attribute__((ext_vector_type(4))) short;

__device__ __forceinline__ unsigned short f2bf(float f) {
  union { float f; unsigned int u; } x; x.f = f;
  unsigned int r = x.u + 0x7fffu + ((x.u >> 16) & 1u);   // RNE
  return (unsigned short)(r >> 16);
}

#if defined(__has_builtin)
#if __has_builtin(__builtin_amdgcn_cvt_pk_bf16_f32)
#define HAVE_PK_BF16 1
#endif
#if __has_builtin(__builtin_amdgcn_exp2f)
#define HAVE_EXP2 1
#endif
#if __has_builtin(__builtin_amdgcn_mfma_f32_16x16x16bf16_1k)
#define HAVE_MFMA_16X16X16_BF16 1
#endif
#endif

__device__ __forceinline__ unsigned int pk_bf16(float a, float b) {
#ifdef HAVE_PK_BF16
  auto v = __builtin_amdgcn_cvt_pk_bf16_f32(a, b);
  union { decltype(v) v2; unsigned int u; } c; c.v2 = v; return c.u;
#else
  return (unsigned int)f2bf(a) | ((unsigned int)f2bf(b) << 16);
#endif
}

// 2^x in one v_exp_f32 (q is pre-scaled by 0.125*log2(e))
__device__ __forceinline__ float fexp2(float x) {
#ifdef HAVE_EXP2
  return __builtin_amdgcn_exp2f(x);
#else
  return exp2f(x);
#endif
}

__device__ __forceinline__ f32x4 mfma16(u16x8 a, u16x8 b, f32x4 c) {
  return __builtin_amdgcn_mfma_f32_16x16x32_bf16((s16x8)a, (s16x8)b, c, 0, 0, 0);
}

// k=16 variant: A/B are 4 bf16 (2 VGPRs); lane l holds row/col l&15,
// k = (l>>4)*4 + j. C/D layout identical to the x32 family.
__device__ __forceinline__ f32x4 mfma16k16(u16x4 a, u16x4 b, f32x4 c) {
#ifdef HAVE_MFMA_16X16X16_BF16
  return __builtin_amdgcn_mfma_f32_16x16x16bf16_1k((s16x4)a, (s16x4)b, c, 0, 0, 0);
#else
  f32x4 d;
  asm("v_mfma_f32_16x16x16_bf16 %0, %1, %2, %3"
      : "=v"(d) : "v"(a), "v"(b), "v"(c));
  return d;
#endif
}

// async global->LDS, 16B/lane; lane i writes LDS base + i*16
__device__ __forceinline__ void gl_lds16(const void* g, void* l) {
  __builtin_amdgcn_global_load_lds(
      (const __attribute__((address_space(1))) void*)g,
      (__attribute__((address_space(3))) void*)l, 16, 0, 0);
}

// ---------------------------------------------------------------------------
// Fused LayerNorm + both weight transposes, one dispatch.
// Blocks [0,2048): LN, 4 rows/block, one row per WAVE (no barriers, no LDS):
//   float4 loads, one-pass mean/var via shfl_xor butterfly, uint2 bf16 stores.
// Blocks [2048,3776): transpose W_qkv (N=2304); [3776,4352): W_out (N=768).
// ---------------------------------------------------------------------------
__global__ __launch_bounds__(256) void lntconv_kernel(
    const float* __restrict__ x, const float* __restrict__ g,
    const float* __restrict__ bb, unsigned short* __restrict__ xn,
    const float* __restrict__ Wq, const float* __restrict__ Wo,
    unsigned short* __restrict__ Wqt, unsigned short* __restrict__ Wot) {
  __shared__ float tile[32][33];               // tconv only
  const int t = threadIdx.x;
  int id = blockIdx.x;
  if (id < 2048) {                             // ---- LN: one row per wave
    const int wid = t >> 6, l = t & 63;
    const int row = id * 4 + wid;
    const float4* xr = (const float4*)(x + (size_t)row * DMODEL);
    float4 xa = xr[l], xb2 = xr[64 + l], xc = xr[128 + l];
    float s = (xa.x + xa.y) + (xa.z + xa.w) + (xb2.x + xb2.y) + (xb2.z + xb2.w)
            + (xc.x + xc.y) + (xc.z + xc.w);
    float q = xa.x * xa.x + xa.y * xa.y + xa.z * xa.z + xa.w * xa.w
            + xb2.x * xb2.x + xb2.y * xb2.y + xb2.z * xb2.z + xb2.w * xb2.w
            + xc.x * xc.x + xc.y * xc.y + xc.z * xc.z + xc.w * xc.w;
#pragma unroll
    for (int o = 32; o; o >>= 1) { s += __shfl_xor(s, o); q += __shfl_xor(q, o); }
    const float mu = s * (1.0f / DMODEL);
    const float var = q * (1.0f / DMODEL) - mu * mu;
    const float rstd = rsqrtf(var + 1e-5f);
    const float4* gp = (const float4*)g;
    const float4* bp = (const float4*)bb;
    uint2* dst = (uint2*)(xn + (size_t)row * DMODEL);
#pragma unroll
    for (int c = 0; c < 3; ++c) {
      float4 xv = (c == 0) ? xa : (c == 1) ? xb2 : xc;
      float4 gv = gp[c * 64 + l], bv = bp[c * 64 + l];
      float y0 = (xv.x - mu) * rstd * gv.x + bv.x;
      float y1 = (xv.y - mu) * rstd * gv.y + bv.y;
      float y2 = (xv.z - mu) * rstd * gv.z + bv.z;
      float y3 = (xv.w - mu) * rstd * gv.w + bv.w;
      uint2 pk; pk.x = pk_bf16(y0, y1); pk.y = pk_bf16(y2, y3);
      dst[c * 64 + l] = pk;
    }
    return;
  }
  // ---- transpose + fp32->bf16: W[K=768][N] -> Wt[N][768]
  id -= 2048;
  const float* W; unsigned short* Wt; int N, n0, k0;
  if (id < 1728) { W = Wq; Wt = Wqt; N = NQKV;   n0 = (id % 72) * 32; k0 = (id / 72) * 32; }
  else { id -= 1728; W = Wo; Wt = Wot; N = DMODEL; n0 = (id % 24) * 32; k0 = (id / 24) * 32; }
  const int tx = t & 31, ty = t >> 5;
#pragma unroll
  for (int r = 0; r < 4; ++r)
    tile[ty + r * 8][tx] = W[(size_t)(k0 + ty + r * 8) * N + n0 + tx];
  __syncthreads();
#pragma unroll
  for (int r = 0; r < 4; ++r)
    Wt[(size_t)(n0 + ty + r * 8) * DMODEL + k0 + tx] = f2bf(tile[tx][ty + r * 8]);
}

// ---------------------------------------------------------------------------
// Fused QKV GEMM, 768 blocks (XCD-bijective, 768 = 8*96), zero tail at
// 3 blocks/CU. Each block:
//  phase 1 (QK, swapped): 128x128 tile of C^T[n_qkv][seq] = Wt · xn^T,
//    a0 = (w%12)*128 in [0,1536), b0 = (w/12)*128.
//  phase 2 (V, original): 64x128 slab of xn @ W_qkv cols [1536,2304):
//    m0 = b0 + ((w%12)&1)*64  <- SUBSET of phase-1's staged xn panel:
//    L2-hot, no cross-XCD refetch. n0 = 1536 + ((w%12)>>1)*128.
//    Bijective: each b0-panel's 12 blocks = 2 halves x 6 vdim-panels.
// Cross-phase prefetch: phase-2 tile 0 staged under phase-1's epilogue.
// ---------------------------------------------------------------------------
__global__ __launch_bounds__(256, 3) void gemm_qkv_kernel(
    const unsigned short* __restrict__ Wt, const unsigned short* __restrict__ xn,
    const float* __restrict__ bias, unsigned short* __restrict__ qb,
    unsigned short* __restrict__ kb, unsigned short* __restrict__ vt) {
  __shared__ alignas(16) unsigned short As[128 * 64];
  __shared__ alignas(16) unsigned short Bs[128 * 64];
  const int t = threadIdx.x, wid = t >> 6, l = t & 63, quad = l >> 4, ll = l & 15;
  const int bid = blockIdx.x;
  const int w = (bid & 7) * 96 + (bid >> 3);   // XCD-bijective (768 = 8*96)
  const int srow = l >> 3, sblk = (l & 7) ^ srow;

  const int wq = w % 12;                       // per-panel sub-index
  const int a0 = wq * 128;                     // phase-1 n_qkv base [0,1536)
  const int b0 = (w / 12) * 128;               // phase-1 seq base
  // phase-2 geometry: seq half INSIDE the phase-1 b0-panel (L2-hot)
  const int m0 = b0 + (wq & 1) * 64;           // seq base (subset of b0-panel)
  const int n0 = 2 * DMODEL + (wq >> 1) * 128; // vdim base in [1536,2304)
  const unsigned short* A2 = xn + (size_t)m0 * DMODEL;
  const unsigned short* B2 = Wt + (size_t)n0 * DMODEL;

  auto stage2 = [&](int k0) {                  // stage one phase-2 tile
#pragma unroll
    for (int cc = 0; cc < 2; ++cc) {           // A: 64 rows = 8 calls
      int call = wid * 2 + cc;
      int r = call * 8 + srow;
      gl_lds16(A2 + (size_t)r * DMODEL + k0 + sblk * 8, &As[call * 512]);
    }
#pragma unroll
    for (int cc = 0; cc < 4; ++cc) {           // B: 128 rows = 16 calls
      int call = wid * 4 + cc;
      int r = call * 8 + srow;
      gl_lds16(B2 + (size_t)r * DMODEL + k0 + sblk * 8, &Bs[call * 512]);
    }
  };

  // ================= phase 1: QK tile (swapped orientation) ================
  {
    const unsigned short* Ap = Wt + (size_t)a0 * DMODEL;
    const unsigned short* Bp = xn + (size_t)b0 * DMODEL;
    const int wa = (wid >> 1) * 64, wb = (wid & 1) * 64;
    f32x4 acc[4][4] = {};
    for (int k0 = 0; k0 < DMODEL; k0 += 64) {
#pragma unroll
      for (int cc = 0; cc < 4; ++cc) {
        int call = wid * 4 + cc;
        int r = call * 8 + srow;
        gl_lds16(Ap + (size_t)r * DMODEL + k0 + sblk * 8, &As[call * 512]);
        gl_lds16(Bp + (size_t)r * DMODEL + k0 + sblk * 8, &Bs[call * 512]);
      }
      __syncthreads();
#pragma unroll
      for (int ks = 0; ks < 2; ++ks) {
        u16x8 af[4], bf[4];
#pragma unroll
        for (int i = 0; i < 4; ++i) {
          int ra = wa + i * 16 + ll, rb = wb + i * 16 + ll;
          int blk = (ks * 4 + quad) ^ (ll & 7);
          af[i] = *(const u16x8*)&As[ra * 64 + blk * 8];
          bf[i] = *(const u16x8*)&Bs[rb * 64 + blk * 8];
        }
#pragma unroll
        for (int mi = 0; mi < 4; ++mi)
#pragma unroll
          for (int ni = 0; ni < 4; ++ni)
            acc[mi][ni] = mfma16(af[mi], bf[ni], acc[mi][ni]);
      }
      __syncthreads();
    }
    // cross-phase prefetch: As/Bs dead for phase 1; epilogue is
    // register-only, so phase-2 tile 0 DMA (L2-hot) flies under the stores.
    stage2(0);
    const bool isq = (a0 < DMODEL);
    unsigned short* dst = isq ? qb : kb;
    const float sc = isq ? 0.18033688f : 1.0f;   // q: 0.125 * log2(e)
#pragma unroll
    for (int mi = 0; mi < 4; ++mi) {
      int row0 = a0 + wa + mi * 16 + quad * 4;   // n_qkv (4 consecutive via r)
      float4 bv = *(const float4*)&bias[row0];
      int rr = isq ? row0 : row0 - DMODEL;
      int h = rr >> 6, d0 = rr & 63;
#pragma unroll
      for (int ni = 0; ni < 4; ++ni) {
        int seq = b0 + wb + ni * 16 + ll;
        int b = seq >> 11, i = seq & 2047;
        uint2 pk;
        pk.x = pk_bf16((acc[mi][ni][0] + bv.x) * sc, (acc[mi][ni][1] + bv.y) * sc);
        pk.y = pk_bf16((acc[mi][ni][2] + bv.z) * sc, (acc[mi][ni][3] + bv.w) * sc);
        *(uint2*)&dst[(size_t)((b * NHEADS + h) * SEQ + i) * DHEAD + d0] = pk;
      }
    }
  }

  // ================= phase 2: V slab (original orientation) ================
  {
    const int wm = (wid >> 1) * 32, wn = (wid & 1) * 64;
    f32x4 acc[2][4] = {};
    for (int k0 = 0; k0 < DMODEL; k0 += 64) {
      __syncthreads();                         // staging for this tile done
#pragma unroll
      for (int ks = 0; ks < 2; ++ks) {
        u16x8 af[2], bf[4];
#pragma unroll
        for (int i = 0; i < 2; ++i) {
          int ra = wm + i * 16 + ll;
          int blk = (ks * 4 + quad) ^ (ll & 7);
          af[i] = *(const u16x8*)&As[ra * 64 + blk * 8];
        }
#pragma unroll
        for (int i = 0; i < 4; ++i) {
          int rb = wn + i * 16 + ll;
          int blk = (ks * 4 + quad) ^ (ll & 7);
          bf[i] = *(const u16x8*)&Bs[rb * 64 + blk * 8];
        }
#pragma unroll
        for (int mi = 0; mi < 2; ++mi)
#pragma unroll
          for (int ni = 0; ni < 4; ++ni)
            acc[mi][ni] = mfma16(af[mi], bf[ni], acc[mi][ni]);
      }
      if (k0 + 64 < DMODEL) {
        __syncthreads();                       // all waves done reading
        stage2(k0 + 64);
      }
    }
#pragma unroll
    for (int mi = 0; mi < 2; ++mi) {
      int gm = m0 + wm + mi * 16 + quad * 4;   // seq, 4 consecutive via r
      int b = gm >> 11, i0 = gm & 2047;
#pragma unroll
      for (int ni = 0; ni < 4; ++ni) {
        int gn = n0 + wn + ni * 16 + ll;
        float bv = bias[gn];
        int rem = gn - 2 * DMODEL;
        int h = rem >> 6, d = rem & 63;
        int bh = b * NHEADS + h;
        uint2 pk;
        pk.x = pk_bf16(acc[mi][ni][0] + bv, acc[mi][ni][1] + bv);
        pk.y = pk_bf16(acc[mi][ni][2] + bv, acc[mi][ni][3] + bv);
        *(uint2*)&vt[((size_t)bh * DHEAD + d) * SEQ + i0] = pk;
      }
    }
  }
}

// ---------------------------------------------------------------------------
// Flash attention (r9-exact), streaming sum-of-exp2 (q pre-scaled).
// grid (16 q-tiles, 48 bh), block 256 (4 waves x 32 q-rows, full 64 keys).
// 3-buffer staging, counted s_waitcnt vmcnt(4) + raw s_barrier: each tile's
// global_load_lds get TWO compute phases to land; never drained to 0
// mid-loop. S^T = K·Q^T C-layout == 16x16x16 A-frag, so PV consumes P from
// registers via k=16 MFMAs; row sums via ones-B MFMA. setprio(1) around
// MFMA clusters. LDS 48 KiB -> 3 blocks/CU.
// XCD relabel: 96 contiguous work-ids per XCD -> 6 bh per 4 MiB L2.
// ---------------------------------------------------------------------------
__global__ __launch_bounds__(256, 3) void attn_kernel(
    const unsigned short* __restrict__ qbuf, const unsigned short* __restrict__ kbuf,
    const unsigned short* __restrict__ vtg, unsigned short* __restrict__ ao) {
  __shared__ alignas(16) unsigned short stage[3][2][KT * DHEAD]; // [buf][K,Vt] 48 KiB
  const int t = threadIdx.x, wid = t >> 6, l = t & 63, quad = l >> 4, ll = l & 15;
  const int Lid = blockIdx.y * 16 + blockIdx.x;
  const int w = (Lid & 7) * 96 + (Lid >> 3);   // bijective XCD relabel (768=8*96)
  const int qt = w & 15, bh = w >> 4;
  const unsigned short* qg  = qbuf + ((size_t)bh * SEQ + qt * 128) * DHEAD;
  const unsigned short* kg0 = kbuf + (size_t)bh * SEQ * DHEAD;
  const unsigned short* vt0 = vtg  + (size_t)bh * DHEAD * SEQ;
  const int srow = l >> 3;                    // 0..7
  const int sblk = (l & 7) ^ srow;            // swizzled source block

  // stage Q (16KB over stage[0], swizzled), hoist fragments, free region
  unsigned short* Qs = &stage[0][0][0];
#pragma unroll
  for (int cc = 0; cc < 4; ++cc) {
    int call = wid * 4 + cc;                  // 16 calls x 8 rows = 128 rows
    gl_lds16(qg + (call * 8 + srow) * 64 + sblk * 8, Qs + call * 512);
  }
  __syncthreads();
  u16x8 qf[2][2];                             // [mi][ks]: this wave's 32 q-rows
#pragma unroll
  for (int mi = 0; mi < 2; ++mi)
#pragma unroll
    for (int ks = 0; ks < 2; ++ks) {
      int r = wid * 32 + mi * 16 + ll;
      int blk = (ks * 4 + quad) ^ (ll & 7);
      qf[mi][ks] = *(const u16x8*)&Qs[r * 64 + blk * 8];
    }
  __syncthreads();                            // all waves done reading Q

  auto stage_tile = [&](int buf, int kt2) {   // 4 gl_lds16 per wave
    const unsigned short* kg = kg0 + (size_t)kt2 * KT * DHEAD;
#pragma unroll
    for (int c = 0; c < 2; ++c) {
      int call = wid * 2 + c;                 // 8 calls x 8 rows = 64 rows
      int r = call * 8 + srow;
      gl_lds16(kg + r * 64 + sblk * 8, &stage[buf][0][call * 512]);
      gl_lds16(vt0 + (size_t)r * SEQ + kt2 * KT + sblk * 8, &stage[buf][1][call * 512]);
    }
  };

  f32x4 oacc[2][4] = {};
  f32x4 osum[2] = {};                         // row-sums via ones-B MFMA
  const u16x4 onesb = {0x3f80u, 0x3f80u, 0x3f80u, 0x3f80u};  // bf16(1.0) x4

  stage_tile(0, 0);                           // 4 loads in flight
  stage_tile(1, 1);                           // 8 in flight
  int bufc = 0, bufs = 2;
  for (int kt2 = 0; kt2 < NT; ++kt2) {
    // own 4 loads for THIS tile retired (in-order); next tile's may remain
    if (kt2 + 1 < NT) asm volatile("s_waitcnt vmcnt(4)" ::: "memory");
    else              asm volatile("s_waitcnt vmcnt(0)" ::: "memory");
    __builtin_amdgcn_s_barrier();             // all waves' tile-kt2 staging done
    if (kt2 + 2 < NT) stage_tile(bufs, kt2 + 2);  // 2-ahead prefetch
    const unsigned short* Ks = &stage[bufc][0][0];
    const unsigned short* Vs = &stage[bufc][1][0];

    // S^T = K Q^T  (lane: qrow = mi*16+ll, keys = ni*16 + quad*4 + r)
    f32x4 st[2][4] = {};
    __builtin_amdgcn_s_setprio(1);
#pragma unroll
    for (int ks = 0; ks < 2; ++ks)
#pragma unroll
      for (int ni = 0; ni < 4; ++ni) {
        int r = ni * 16 + ll;
        int blk = (ks * 4 + quad) ^ (ll & 7);
        u16x8 kf = *(const u16x8*)&Ks[r * 64 + blk * 8];
        st[0][ni] = mfma16(kf, qf[0][ks], st[0][ni]);
        st[1][ni] = mfma16(kf, qf[1][ks], st[1][ni]);
      }
    __builtin_amdgcn_s_setprio(0);

    // p = 2^s packed to bf16 in-register == 16x16x16 A-frag for this ni.
    // O += P·V via k=16 MFMAs; Σp via ones-B MFMA (rides the matrix pipe).
#pragma unroll
    for (int ni = 0; ni < 4; ++ni) {
      u16x4 pf[2];
#pragma unroll
      for (int mi = 0; mi < 2; ++mi) {
        float p0 = fexp2(st[mi][ni][0]);
        float p1 = fexp2(st[mi][ni][1]);
        float p2 = fexp2(st[mi][ni][2]);
        float p3 = fexp2(st[mi][ni][3]);
        union { uint2 u; u16x4 v; } cv;
        cv.u.x = pk_bf16(p0, p1);
        cv.u.y = pk_bf16(p2, p3);
        pf[mi] = cv.v;
      }
      // B-frag: V[key = ni*16+quad*4+j][d = di*16+ll]; 8B reads off the
      // staged layout (phys 16B-unit = logical ^ (d&7)); shared across mi.
      const int voff = (((ni * 2 + (quad >> 1)) ^ (ll & 7)) << 3) + (quad & 1) * 4;
      __builtin_amdgcn_s_setprio(1);
      osum[0] = mfma16k16(pf[0], onesb, osum[0]);
      osum[1] = mfma16k16(pf[1], onesb, osum[1]);
#pragma unroll
      for (int di = 0; di < 4; ++di) {
        u16x4 vf = *(const u16x4*)&Vs[(di * 16 + ll) * 64 + voff];
        oacc[0][di] = mfma16k16(pf[0], vf, oacc[0][di]);
        oacc[1][di] = mfma16k16(pf[1], vf, oacc[1][di]);
      }
      __builtin_amdgcn_s_setprio(0);
    }
    bufc = (bufc == 2) ? 0 : bufc + 1;
    bufs = (bufs == 2) ? 0 : bufs + 1;
  }

  // epilogue: O C-layout row = quad*4+r, col d = di*16+ll; osum rows match,
  // so the per-row denominator is already in the right lane — no shuffles.
  const int b = bh / NHEADS, h = bh - b * NHEADS;
#pragma unroll
  for (int mi = 0; mi < 2; ++mi) {
#pragma unroll
    for (int r = 0; r < 4; ++r) {
      float inv = 1.0f / osum[mi][r];
      int row = qt * 128 + wid * 32 + mi * 16 + quad * 4 + r;
      size_t base = ((size_t)(b * SEQ + row)) * DMODEL + h * DHEAD;
#pragma unroll
      for (int di = 0; di < 4; ++di)
        ao[base + di * 16 + ll] = f2bf(oacc[mi][di][r] * inv);
    }
  }
}

// ---------------------------------------------------------------------------
// GEMM-OUT (swapped orientation, 64x128 tile): C^T[n_out][seq] = Woutt·ao^T.
// 768 blocks, XCD-bijective relabel (768 = 8*96): each XCD keeps 8 seq-
// panels of ao (1.5 MiB) + full Woutt (1.2 MiB) L2-resident.
// Lane holds 4 consecutive n_out for one seq -> packed float4 stores.
// ---------------------------------------------------------------------------
__global__ __launch_bounds__(256, 3) void gemm_out_kernel(
    const unsigned short* __restrict__ Wt, const unsigned short* __restrict__ ao,
    const float* __restrict__ bias, float* __restrict__ out) {
  __shared__ alignas(16) unsigned short As[64 * 64];
  __shared__ alignas(16) unsigned short Bs[128 * 64];
  const int t = threadIdx.x, wid = t >> 6, l = t & 63, quad = l >> 4, ll = l & 15;
  const int bid = blockIdx.x;
  const int w = (bid & 7) * 96 + (bid >> 3);   // XCD-bijective relabel (768=8*96)
  const int a0 = (w % 12) * 64;    // n_out base (12 tiles)
  const int b0 = (w / 12) * 128;   // seq base (64 tiles)
  const int wa = (wid >> 1) * 32, wb = (wid & 1) * 64;
  const int srow = l >> 3, sblk = (l & 7) ^ srow;
  f32x4 acc[2][4] = {};
  for (int k0 = 0; k0 < DMODEL; k0 += 64) {
#pragma unroll
    for (int cc = 0; cc < 6; ++cc) {           // 24 calls: 8 A + 16 B
      int call = wid * 6 + cc;
      if (call < 8) {
        int r = call * 8 + srow;
        gl_lds16(Wt + (size_t)(a0 + r) * DMODEL + k0 + sblk * 8, &As[call * 512]);
      } else {
        int c2 = call - 8;
        int r = c2 * 8 + srow;
        gl_lds16(ao + (size_t)(b0 + r) * DMODEL + k0 + sblk * 8, &Bs[c2 * 512]);
      }
    }
    __syncthreads();
#pragma unroll
    for (int ks = 0; ks < 2; ++ks) {
      u16x8 af[2], bf[4];
#pragma unroll
      for (int i = 0; i < 2; ++i) {
        int ra = wa + i * 16 + ll;
        int blk = (ks * 4 + quad) ^ (ll & 7);
        af[i] = *(const u16x8*)&As[ra * 64 + blk * 8];
      }
#pragma unroll
      for (int i = 0; i < 4; ++i) {
        int rb = wb + i * 16 + ll;
        int blk = (ks * 4 + quad) ^ (ll & 7);
        bf[i] = *(const u16x8*)&Bs[rb * 64 + blk * 8];
      }
#pragma unroll
      for (int mi = 0; mi < 2; ++mi)
#pragma unroll
        for (int ni = 0; ni < 4; ++ni)
          acc[mi][ni] = mfma16(af[mi], bf[ni], acc[mi][ni]);
    }
    __syncthreads();
  }
#pragma unroll
  for (int mi = 0; mi < 2; ++mi) {
    int row0 = a0 + wa + mi * 16 + quad * 4;   // n_out, 4 consecutive via r
    float4 bv = *(const float4*)&bias[row0];
#pragma unroll
    for (int ni = 0; ni < 4; ++ni) {
      int seq = b0 + wb + ni * 16 + ll;
      float4 o;
      o.x = acc[mi][ni][0] + bv.x;
      o.y = acc[mi][ni][1] + bv.y;
      o.z = acc[mi][ni][2] + bv.z;
      o.w = acc[mi][ni][3] + bv.w;
      *(float4*)&out[(size_t)seq * DMODEL + row0] = o;
    }
  }
}

// ---------------------------------------------------------------------------
// launch
// ---------------------------------------------------------------------------
extern "C" void kernel_launch(void* const* d_in, const int* in_sizes, int n_in,
                              void* d_out, int out_size, void* d_ws, size_t ws_size,
                              hipStream_t stream) {
  const float* x     = (const float*)d_in[0];
  const float* ln_g  = (const float*)d_in[1];
  const float* ln_b  = (const float*)d_in[2];
  const float* W_qkv = (const float*)d_in[3];
  const float* b_qkv = (const float*)d_in[4];
  const float* W_out = (const float*)d_in[5];
  const float* b_out = (const float*)d_in[6];
  float* out = (float*)d_out;

  char* ws = (char*)d_ws;
  unsigned short* xn    = (unsigned short*)(ws);               // 12,582,912 B
  unsigned short* wqkvt = (unsigned short*)(ws + 12582912);    //  3,538,944 B
  unsigned short* woutt = (unsigned short*)(ws + 16121856);    //  1,179,648 B
  unsigned short* qb    = (unsigned short*)(ws + 17301504);    // 12,582,912 B
  unsigned short* kb    = (unsigned short*)(ws + 29884416);    // 12,582,912 B
  unsigned short* vt    = (unsigned short*)(ws + 42467328);    // 12,582,912 B
  unsigned short* ao    = xn;  // xn dead after the QKV GEMMs

  lntconv_kernel<<<2048 + 2304, 256, 0, stream>>>(x, ln_g, ln_b, xn,
                                                  W_qkv, W_out, wqkvt, woutt);
  gemm_qkv_kernel<<<768, 256, 0, stream>>>(wqkvt, xn, b_qkv, qb, kb, vt);
  attn_kernel<<<dim3(SEQ / 128, NBATCH * NHEADS), 256, 0, stream>>>(qb, kb, vt, ao);
  gemm_out_kernel<<<768, 256, 0, stream>>>(woutt, ao, b_out, out);
}